// Round 4
// baseline (264.264 us; speedup 1.0000x reference)
//
#include <hip/hip_runtime.h>

#define TT 512
#define BB 512
#define NN 64
#define LN2F 0.69314718055994530942f

__device__ __forceinline__ float wave_max(float v) {
    #pragma unroll
    for (int off = 32; off > 0; off >>= 1)
        v = fmaxf(v, __shfl_xor(v, off, 64));
    return v;
}

__device__ __forceinline__ float wave_sum(float v) {
    #pragma unroll
    for (int off = 32; off > 0; off >>= 1)
        v += __shfl_xor(v, off, 64);
    return v;
}

__device__ __forceinline__ int wave_sum_i(int v) {
    #pragma unroll
    for (int off = 32; off > 0; off >>= 1)
        v += __shfl_xor(v, off, 64);
    return v;
}

__device__ __forceinline__ float bcast_lane(float v, int lane) {
    return __uint_as_float(__builtin_amdgcn_readlane(__float_as_uint(v), lane));
}

// Zero the scalar output (harness poisons d_out with 0xAA before every launch).
__global__ void zero_kernel(float* __restrict__ out) {
    if (threadIdx.x == 0 && blockIdx.x == 0) out[0] = 0.0f;
}

// Forward algorithm in the EXP domain: one wave per batch element, lane = state k.
// State: u_k = exp(alpha_k - S), S tracked as m0 + ln2 * e_sum (wave-uniform).
// Step: y_k = sum_j u_j * E[j,k];  u'_k = ldexp(y_k * w_k, -e);  e = exp2 of lane0's y*w.
// w_k = exp(emit[t,b,k]) is computed OFF the serial chain (3-deep prefetch pipeline).
// Cross-lane broadcast of u via readlanes batched in chunks of 16 (sched_barrier
// fences) so the v_readlane->SGPR-consume hazard (~5 cyc/pair interleaved) vanishes.
// Gold score fused into the epilogue (one wave handles its batch's 512 steps).
__global__ __launch_bounds__(64) void crf_fwd_kernel(
    const float* __restrict__ emit,
    const float* __restrict__ trans,
    const float* __restrict__ strans,
    const float* __restrict__ etrans,
    const int*   __restrict__ target,
    const void*  __restrict__ maskp,
    float* __restrict__ out)
{
    const int b = blockIdx.x;
    const int k = threadIdx.x;

    const int*           mi32 = (const int*)maskp;
    const unsigned char* mi8  = (const unsigned char*)maskp;
    // mask[0,:] is all-true (lengths >= 1): byte encoding -> word0 == 0x01010101.
    const bool bytemode = (mi32[0] == 0x01010101);

    // len[b] = sum_t mask[t,b] (mask monotone per column) — one-time cost.
    int cnt = 0;
    #pragma unroll
    for (int i = 0; i < TT / 64; ++i) {
        const size_t tb = (size_t)(i * 64 + k) * BB + b;
        cnt += bytemode ? (mi8[tb] != 0) : (mi32[tb] != 0);
    }
    const int len = wave_sum_i(cnt);   // wave-uniform

    // E[j] = exp(trans[j][k]); |trans| small, E in [~0.55, ~1.8]. 64 VGPRs.
    float E[NN];
    #pragma unroll
    for (int j = 0; j < NN; ++j)
        E[j] = __expf(trans[j * NN + k]);

    // t = 0: u = exp(alpha0 - m0)
    const float alpha0 = emit[(size_t)b * NN + k] + strans[k];
    const float m0 = bcast_lane(alpha0, 0);
    float u = __expf(alpha0 - m0);
    int e_sum = 0;

    // emit prefetch pipeline, depth 3 (covers ~3 step-times of load latency).
    float f0 = emit[((size_t)(1 < TT ? 1 : TT - 1) * BB + b) * NN + k];
    float f1 = emit[((size_t)(2 < TT ? 2 : TT - 1) * BB + b) * NN + k];
    float f2 = emit[((size_t)(3 < TT ? 3 : TT - 1) * BB + b) * NN + k];
    float w = __expf(f0);   // w for t = 1
    f0 = f1; f1 = f2;

    for (int t = 1; t < len; ++t) {
        // issue load for t+3 (clamped; overshoot past len is harmless)
        const int tf = (t + 3 < TT) ? (t + 3) : (TT - 1);
        const float fnew = emit[((size_t)tf * BB + b) * NN + k];
        const float wloc = w;
        const float wn = __expf(f0);   // w for t+1 — independent of the u-chain
        f0 = f1; f1 = fnew;

        // y_k = sum_j u_j * E[j] — readlanes batched 16 at a time, then FMAs.
        float s0 = 0.f, s1 = 0.f, s2 = 0.f, s3 = 0.f;
        #pragma unroll
        for (int c = 0; c < 4; ++c) {
            float ps[16];
            #pragma unroll
            for (int j = 0; j < 16; ++j)
                ps[j] = bcast_lane(u, 16 * c + j);
            __builtin_amdgcn_sched_barrier(0);
            #pragma unroll
            for (int j = 0; j < 16; j += 4) {
                s0 = fmaf(ps[j + 0], E[16 * c + j + 0], s0);
                s1 = fmaf(ps[j + 1], E[16 * c + j + 1], s1);
                s2 = fmaf(ps[j + 2], E[16 * c + j + 2], s2);
                s3 = fmaf(ps[j + 3], E[16 * c + j + 3], s3);
            }
            __builtin_amdgcn_sched_barrier(0);
        }
        const float y = ((s0 + s1) + (s2 + s3)) * wloc;   // > 0 always (E>0, u_max>0)

        // power-of-2 rescale from lane0's exponent (SALU bit-extract, no transcendentals)
        const int e = (int)((__builtin_amdgcn_readfirstlane(__float_as_uint(y)) >> 23) & 0xff) - 127;
        u = ldexpf(y, -e);
        e_sum += e;
        w = wn;
    }

    // logZ_b = S + logsumexp_k(log(u_k) + etrans[k]),  S = m0 + ln2*e_sum
    const float la = __logf(u) + etrans[k];   // u==0 -> -inf -> exp -> 0: fine
    const float m2 = wave_max(la);
    const float sm = wave_sum(__expf(la - m2));
    const float logZ_b = m0 + LN2F * (float)e_sum + m2 + __logf(sm);

    // ---- fused gold score for batch b: lane k covers t = 64*i + k ----
    int tvals[TT / 64];
    #pragma unroll
    for (int i = 0; i < TT / 64; ++i)
        tvals[i] = target[(size_t)(64 * i + k) * BB + b];

    float g = 0.f;
    int prev_last = 0;
    #pragma unroll
    for (int i = 0; i < TT / 64; ++i) {
        const int t = 64 * i + k;
        const int tgt = tvals[i];
        int tprev = __shfl_up(tvals[i], 1, 64);
        if (k == 0) tprev = prev_last;                       // carry across i
        prev_last = __builtin_amdgcn_readlane(tvals[i], 63);
        if (t < len) {
            float v = emit[((size_t)t * BB + b) * NN + tgt];
            v += (t == 0) ? strans[tgt] : trans[tprev * NN + tgt];
            if (t == len - 1) v += etrans[tgt];
            g += v;
        }
    }
    g = wave_sum(g);

    if (k == 0) atomicAdd(out, logZ_b - g);
}

extern "C" void kernel_launch(void* const* d_in, const int* in_sizes, int n_in,
                              void* d_out, int out_size, void* d_ws, size_t ws_size,
                              hipStream_t stream) {
    const float* emit   = (const float*)d_in[0];
    const float* trans  = (const float*)d_in[1];
    const float* strans = (const float*)d_in[2];
    const float* etrans = (const float*)d_in[3];
    const int*   target = (const int*)d_in[4];
    const void*  mask   = d_in[5];
    float* out = (float*)d_out;

    hipLaunchKernelGGL(zero_kernel, dim3(1), dim3(64), 0, stream, out);
    hipLaunchKernelGGL(crf_fwd_kernel, dim3(BB), dim3(64), 0, stream,
                       emit, trans, strans, etrans, target, mask, out);
}

// Round 6
// 237.537 us; speedup vs baseline: 1.1125x; 1.1125x over previous
//
#include <hip/hip_runtime.h>

#define TT 512
#define BB 512
#define NN 64
#define LN2F 0.69314718055994530942f

typedef _Float16 half8_t __attribute__((ext_vector_type(8)));
typedef float    f32x4   __attribute__((ext_vector_type(4)));

union AFrag { int u[4]; half8_t h; };

__device__ __forceinline__ float wave_max(float v) {
    #pragma unroll
    for (int off = 32; off > 0; off >>= 1)
        v = fmaxf(v, __shfl_xor(v, off, 64));
    return v;
}

__device__ __forceinline__ float wave_sum(float v) {
    #pragma unroll
    for (int off = 32; off > 0; off >>= 1)
        v += __shfl_xor(v, off, 64);
    return v;
}

__device__ __forceinline__ int wave_sum_i(int v) {
    #pragma unroll
    for (int off = 32; off > 0; off >>= 1)
        v += __shfl_xor(v, off, 64);
    return v;
}

__device__ __forceinline__ float bcast_lane(float v, int lane) {
    return __uint_as_float(__builtin_amdgcn_readlane(__float_as_uint(v), lane));
}

// Zero the scalar output (harness poisons d_out with 0xAA before every launch).
__global__ void zero_kernel(float* __restrict__ out) {
    if (threadIdx.x == 0 && blockIdx.x == 0) out[0] = 0.0f;
}

// Forward algorithm in the EXP domain, matvec via MFMA.
// State u_k = exp(alpha_k - S); step: y = (u . 0.25*E)*w ; u' = ldexp(y, -e);
// S' = S + (e + 2)*ln2   <-- the +2 accounts for the 0.25 = 2^-2 folded into
// the B fragments (r5 bug: missing +2 gave a deficit of exactly ln4 * sum(len-1),
// matching the observed absmax 186368 to ~1 sigma — layouts verified correct).
// y(1x64) = u(1x64) * E(64x64) via 4 column-groups x 2 K-halves of
// v_mfma_f32_16x16x32_f16 with A = u replicated across all 16 rows:
//   A[m][k2] = u_k2  (A-layout: m=lane&15, k2=8*(lane>>4)+j)
//   B[k2][n] = 0.25*exp(trans[k2][n])  (n=lane&15, k2=8*(lane>>4)+j)
// All 8 MFMAs are independent (zero C both K-halves; halves summed at extract)
// so the MFMA pipe can overlap them. All D rows equal -> lane k selects
// col k&15 of group k>>4 via cndmasks.
__global__ __launch_bounds__(64) void crf_fwd_kernel(
    const float* __restrict__ emit,
    const float* __restrict__ trans,
    const float* __restrict__ strans,
    const float* __restrict__ etrans,
    const int*   __restrict__ target,
    const void*  __restrict__ maskp,
    float* __restrict__ out)
{
    const int b = blockIdx.x;
    const int k = threadIdx.x;

    const int*           mi32 = (const int*)maskp;
    const unsigned char* mi8  = (const unsigned char*)maskp;
    // mask[0,:] is all-true (lengths >= 1): byte encoding -> word0 == 0x01010101.
    const bool bytemode = (mi32[0] == 0x01010101);

    // len[b] = sum_t mask[t,b] (mask monotone per column) — one-time cost.
    int cnt = 0;
    #pragma unroll
    for (int i = 0; i < TT / 64; ++i) {
        const size_t tb = (size_t)(i * 64 + k) * BB + b;
        cnt += bytemode ? (mi8[tb] != 0) : (mi32[tb] != 0);
    }
    const int len = wave_sum_i(cnt);   // wave-uniform

    const int q   = k >> 4;
    const int nlo = k & 15;
    const bool odd  = (k & 1)  != 0;
    const bool bit4 = (k & 16) != 0;
    const bool bit5 = (k & 32) != 0;

    // B fragments: Bf[g][kh], element j = 0.25*exp(trans[(32kh+8q+j)][16g+nlo]).
    half8_t Bf[4][2];
    #pragma unroll
    for (int g = 0; g < 4; ++g) {
        #pragma unroll
        for (int kh = 0; kh < 2; ++kh) {
            AFrag bf;
            #pragma unroll
            for (int jp = 0; jp < 4; ++jp) {
                const int krow = 32 * kh + 8 * q + 2 * jp;
                const float e0 = 0.25f * __expf(trans[(krow + 0) * NN + 16 * g + nlo]);
                const float e1 = 0.25f * __expf(trans[(krow + 1) * NN + 16 * g + nlo]);
                bf.u[jp] = __builtin_bit_cast(int, __builtin_amdgcn_cvt_pkrtz(e0, e1));
            }
            Bf[g][kh] = bf.h;
        }
    }

    // bpermute byte-addresses: A frag (kh, reg r) needs the f16 pair
    // (u_{32kh+8q+2r}, u_{...+2r+1}), held by source lane 32kh+8q+2r.
    int addrs[8];
    #pragma unroll
    for (int kh = 0; kh < 2; ++kh)
        #pragma unroll
        for (int r = 0; r < 4; ++r)
            addrs[4 * kh + r] = 128 * kh + 32 * q + 8 * r;

    const f32x4 zero4 = {0.f, 0.f, 0.f, 0.f};

    // t = 0: u = exp(alpha0 - m0)
    const float alpha0 = emit[(size_t)b * NN + k] + strans[k];
    const float m0 = bcast_lane(alpha0, 0);
    float u = __expf(alpha0 - m0);
    int e_sum = 0;

    // emit prefetch pipeline, depth 6.
    // invariant at top of iteration t: w = exp(emit[t]); f0..f5 = emit[t+1..t+6]
    float f0 = emit[((size_t)2 * BB + b) * NN + k];
    float f1 = emit[((size_t)3 * BB + b) * NN + k];
    float f2 = emit[((size_t)4 * BB + b) * NN + k];
    float f3 = emit[((size_t)5 * BB + b) * NN + k];
    float f4 = emit[((size_t)6 * BB + b) * NN + k];
    float f5 = emit[((size_t)7 * BB + b) * NN + k];
    float w = __expf(emit[((size_t)1 * BB + b) * NN + k]);

    for (int t = 1; t < len; ++t) {
        // prefetch raw emit for t+7 (clamped; overshoot past len harmless)
        const int tf = (t + 7 < TT) ? (t + 7) : (TT - 1);
        const float fnew = emit[((size_t)tf * BB + b) * NN + k];
        const float wloc = w;
        const float wn = __expf(f0);   // w for t+1 — off the u-chain
        f0 = f1; f1 = f2; f2 = f3; f3 = f4; f4 = f5; f5 = fnew;

        // pack f16 pair (u_{2m}, u_{2m+1}) in every lane (m = k>>1):
        // DPP quad_perm(1,0,3,2) = xor-1 swap, pure VALU.
        const float uo = __int_as_float(
            __builtin_amdgcn_mov_dpp(__float_as_int(u), 0xB1, 0xF, 0xF, true));
        const float pe = odd ? uo : u;
        const float po = odd ? u : uo;
        const int pkv = __builtin_bit_cast(int, __builtin_amdgcn_cvt_pkrtz(pe, po));

        // gather A fragments (8 bpermutes)
        AFrag a0f, a1f;
        #pragma unroll
        for (int r = 0; r < 4; ++r) {
            a0f.u[r] = __builtin_amdgcn_ds_bpermute(addrs[r],     pkv);
            a1f.u[r] = __builtin_amdgcn_ds_bpermute(addrs[4 + r], pkv);
        }

        // y = u * 0.25E : 4 column groups x 2 independent K-halves
        const f32x4 accA0 = __builtin_amdgcn_mfma_f32_16x16x32_f16(a0f.h, Bf[0][0], zero4, 0, 0, 0);
        const f32x4 accA1 = __builtin_amdgcn_mfma_f32_16x16x32_f16(a0f.h, Bf[1][0], zero4, 0, 0, 0);
        const f32x4 accA2 = __builtin_amdgcn_mfma_f32_16x16x32_f16(a0f.h, Bf[2][0], zero4, 0, 0, 0);
        const f32x4 accA3 = __builtin_amdgcn_mfma_f32_16x16x32_f16(a0f.h, Bf[3][0], zero4, 0, 0, 0);
        const f32x4 accB0 = __builtin_amdgcn_mfma_f32_16x16x32_f16(a1f.h, Bf[0][1], zero4, 0, 0, 0);
        const f32x4 accB1 = __builtin_amdgcn_mfma_f32_16x16x32_f16(a1f.h, Bf[1][1], zero4, 0, 0, 0);
        const f32x4 accB2 = __builtin_amdgcn_mfma_f32_16x16x32_f16(a1f.h, Bf[2][1], zero4, 0, 0, 0);
        const f32x4 accB3 = __builtin_amdgcn_mfma_f32_16x16x32_f16(a1f.h, Bf[3][1], zero4, 0, 0, 0);

        // lane k takes column-group g = k>>4 (all D rows identical)
        const float sAlo = bit4 ? accA1[0] : accA0[0];
        const float sAhi = bit4 ? accA3[0] : accA2[0];
        const float sBlo = bit4 ? accB1[0] : accB0[0];
        const float sBhi = bit4 ? accB3[0] : accB2[0];
        const float y = ((bit5 ? sAhi : sAlo) + (bit5 ? sBhi : sBlo)) * wloc;

        // power-of-2 rescale from lane0's exponent; +2 restores the 2^-2
        // folded into the B fragments (exact bookkeeping).
        const int e = (int)((__builtin_amdgcn_readfirstlane(__float_as_uint(y)) >> 23) & 0xff) - 127;
        u = ldexpf(y, -e);
        e_sum += e + 2;
        w = wn;
    }

    // logZ_b = S + logsumexp_k(log(u_k) + etrans[k]),  S = m0 + ln2*e_sum
    const float la = __logf(u) + etrans[k];   // u==0 -> -inf -> exp -> 0: fine
    const float m2 = wave_max(la);
    const float sm = wave_sum(__expf(la - m2));
    const float logZ_b = m0 + LN2F * (float)e_sum + m2 + __logf(sm);

    // ---- fused gold score for batch b: lane k covers t = 64*i + k ----
    int tvals[TT / 64];
    #pragma unroll
    for (int i = 0; i < TT / 64; ++i)
        tvals[i] = target[(size_t)(64 * i + k) * BB + b];

    float g = 0.f;
    int prev_last = 0;
    #pragma unroll
    for (int i = 0; i < TT / 64; ++i) {
        const int t = 64 * i + k;
        const int tgt = tvals[i];
        int tprev = __shfl_up(tvals[i], 1, 64);
        if (k == 0) tprev = prev_last;                       // carry across i
        prev_last = __builtin_amdgcn_readlane(tvals[i], 63);
        if (t < len) {
            float v = emit[((size_t)t * BB + b) * NN + tgt];
            v += (t == 0) ? strans[tgt] : trans[tprev * NN + tgt];
            if (t == len - 1) v += etrans[tgt];
            g += v;
        }
    }
    g = wave_sum(g);

    if (k == 0) atomicAdd(out, logZ_b - g);
}

extern "C" void kernel_launch(void* const* d_in, const int* in_sizes, int n_in,
                              void* d_out, int out_size, void* d_ws, size_t ws_size,
                              hipStream_t stream) {
    const float* emit   = (const float*)d_in[0];
    const float* trans  = (const float*)d_in[1];
    const float* strans = (const float*)d_in[2];
    const float* etrans = (const float*)d_in[3];
    const int*   target = (const int*)d_in[4];
    const void*  mask   = d_in[5];
    float* out = (float*)d_out;

    hipLaunchKernelGGL(zero_kernel, dim3(1), dim3(64), 0, stream, out);
    hipLaunchKernelGGL(crf_fwd_kernel, dim3(BB), dim3(64), 0, stream,
                       emit, trans, strans, etrans, target, mask, out);
}